// Round 2
// baseline (763.114 us; speedup 1.0000x reference)
//
#include <hip/hip_runtime.h>

#define NN 50000
#define NE 400000
#define NBATCH 8
#define DD 128
#define SCAN_BLK 1024

typedef unsigned short u16;
typedef __attribute__((ext_vector_type(8))) short bf16x8;
typedef __attribute__((ext_vector_type(8))) unsigned short u16x8;
typedef __attribute__((ext_vector_type(4))) unsigned short u16x4;
typedef __attribute__((ext_vector_type(4))) float f32x4;

__device__ __forceinline__ u16 f2bf(float f) {
  union { float f; unsigned u; } a; a.f = f;
  unsigned r = a.u + 0x7fffu + ((a.u >> 16) & 1u);
  return (u16)(r >> 16);
}

__device__ __forceinline__ u16x8 cvt8(const float* p) {
  f32x4 a = *(const f32x4*)p;
  f32x4 b = *(const f32x4*)(p + 4);
  u16x8 r;
  r[0]=f2bf(a[0]); r[1]=f2bf(a[1]); r[2]=f2bf(a[2]); r[3]=f2bf(a[3]);
  r[4]=f2bf(b[0]); r[5]=f2bf(b[1]); r[6]=f2bf(b[2]); r[7]=f2bf(b[3]);
  return r;
}

// Convert+transpose fp32 weight [K][128] -> bf16 chunked [K/128][128 n][128 k]
__global__ void wconv_kernel(const float* __restrict__ src, u16* __restrict__ dst, int K) {
  int idx = blockIdx.x * 256 + threadIdx.x;
  if (idx >= K * 128) return;
  int k = idx >> 7, n = idx & 127;
  dst[((k >> 7) << 14) + (n << 7) + (k & 127)] = f2bf(src[idx]);
}

__global__ void xconv_kernel(const float* __restrict__ x, u16* __restrict__ xbf, int total4) {
  int i = blockIdx.x * 256 + threadIdx.x;
  if (i >= total4) return;
  f32x4 v = ((const f32x4*)x)[i];
  u16x4 o; o[0]=f2bf(v[0]); o[1]=f2bf(v[1]); o[2]=f2bf(v[2]); o[3]=f2bf(v[3]);
  ((u16x4*)xbf)[i] = o;
}

// ---------- CSR prep: histogram by col, batch histograms ----------
__global__ void ehist_kernel(const int* __restrict__ edge_index, const int* __restrict__ batch,
                             int* __restrict__ cnt, unsigned* __restrict__ ecnt) {
  __shared__ unsigned h[NBATCH];
  if (threadIdx.x < NBATCH) h[threadIdx.x] = 0;
  __syncthreads();
  int e = blockIdx.x * 256 + threadIdx.x;
  if (e < NE) {
    int col = edge_index[NE + e];
    atomicAdd(&cnt[col], 1);
    int row = edge_index[e];
    atomicAdd(&h[batch[row]], 1u);
  }
  __syncthreads();
  if (threadIdx.x < NBATCH) atomicAdd(&ecnt[threadIdx.x], h[threadIdx.x]);
}

__global__ void nhist_kernel(const int* __restrict__ batch, unsigned* __restrict__ ncnt) {
  __shared__ unsigned h[NBATCH];
  if (threadIdx.x < NBATCH) h[threadIdx.x] = 0;
  __syncthreads();
  int i = blockIdx.x * 256 + threadIdx.x;
  if (i < NN) atomicAdd(&h[batch[i]], 1u);
  __syncthreads();
  if (threadIdx.x < NBATCH) atomicAdd(&ncnt[threadIdx.x], h[threadIdx.x]);
}

// ---------- exclusive prefix sum over cnt[NN] -> offs ----------
__global__ void scan1_kernel(const int* __restrict__ cnt, int* __restrict__ offs,
                             int* __restrict__ bsum, int n) {
  __shared__ int lds[256];
  int b0 = blockIdx.x * SCAN_BLK;
  int t = threadIdx.x;
  int i0 = b0 + t * 4;
  int v[4]; int s = 0;
#pragma unroll
  for (int k = 0; k < 4; ++k) { int idx = i0 + k; int c = (idx < n) ? cnt[idx] : 0; v[k] = s; s += c; }
  lds[t] = s;
  __syncthreads();
  for (int off = 1; off < 256; off <<= 1) {
    int x = (t >= off) ? lds[t - off] : 0;
    __syncthreads();
    lds[t] += x;
    __syncthreads();
  }
  int texcl = (t > 0) ? lds[t - 1] : 0;
#pragma unroll
  for (int k = 0; k < 4; ++k) { int idx = i0 + k; if (idx < n) offs[idx] = texcl + v[k]; }
  if (t == 255) bsum[blockIdx.x] = lds[255];
}

__global__ void scan2_kernel(int* __restrict__ bsum, int nb) {
  if (threadIdx.x == 0) {
    int s = 0;
    for (int i = 0; i < nb; ++i) { int c = bsum[i]; bsum[i] = s; s += c; }
  }
}

__global__ void scan3_kernel(int* __restrict__ offs, int* __restrict__ cursor,
                             const int* __restrict__ bsum, int n, int total) {
  int i = blockIdx.x * 256 + threadIdx.x;
  if (i < n) {
    int v = offs[i] + bsum[i / SCAN_BLK];
    offs[i] = v;
    cursor[i] = v;
  }
  if (i == 0) offs[n] = total;
}

__global__ void scatter_kernel(const int* __restrict__ edge_index, int* __restrict__ cursor,
                               int* __restrict__ perm) {
  int e = blockIdx.x * 256 + threadIdx.x;
  if (e < NE) {
    int col = edge_index[NE + e];
    int pos = atomicAdd(&cursor[col], 1);
    perm[pos] = e;
  }
}

// ---------------- Edge MLP kernel: tile = 128 edges ----------------
__global__ __launch_bounds__(256, 2) void edge_kernel(
    const u16* __restrict__ xbf, const float* __restrict__ edge_attr,
    const float* __restrict__ u, const int* __restrict__ edge_index,
    const int* __restrict__ batch,
    const u16* __restrict__ w1, const u16* __restrict__ w2, const u16* __restrict__ w3,
    const float* __restrict__ b1, const float* __restrict__ b2, const float* __restrict__ b3,
    float* __restrict__ edge_out, float* __restrict__ esum)
{
  __shared__ u16 As[128][136];
  __shared__ u16 Bs[128][136];
  __shared__ float red[NBATCH][128];
  __shared__ int rows_s[128], cols_s[128], ebat_s[128];

  const int tid = threadIdx.x;
  const int lane = tid & 63;
  const int wave = tid >> 6;
  const int wr = wave >> 1, wc = wave & 1;
  const int lr = lane & 15;
  const int lkb = lane >> 4;
  const int e0 = blockIdx.x * 128;

  if (tid < 128) {
    int r = edge_index[e0 + tid];
    int c = edge_index[NE + e0 + tid];
    rows_s[tid] = r; cols_s[tid] = c;
    ebat_s[tid] = batch[r];
  }
  for (int i = tid; i < NBATCH * 128; i += 256) (&red[0][0])[i] = 0.f;

  f32x4 acc[4][4];
#pragma unroll
  for (int m = 0; m < 4; ++m)
#pragma unroll
    for (int n = 0; n < 4; ++n) { acc[m][n][0]=0.f; acc[m][n][1]=0.f; acc[m][n][2]=0.f; acc[m][n][3]=0.f; }

  __syncthreads();

  // ---- layer 1: K=512, 4 chunks of 128
  for (int c = 0; c < 4; ++c) {
    for (int i = tid; i < 128 * 16; i += 256) {
      int r = i >> 4, q = (i & 15) << 3;
      u16x8 v;
      if (c == 0)      v = *(const u16x8*)(xbf + (size_t)rows_s[r] * DD + q);
      else if (c == 1) v = *(const u16x8*)(xbf + (size_t)cols_s[r] * DD + q);
      else if (c == 2) v = cvt8(edge_attr + (size_t)(e0 + r) * DD + q);
      else             v = cvt8(u + (size_t)ebat_s[r] * DD + q);
      *(u16x8*)&As[r][q] = v;
      *(u16x8*)&Bs[r][q] = *(const u16x8*)(w1 + (c << 14) + (r << 7) + q);
    }
    __syncthreads();
#pragma unroll
    for (int kk = 0; kk < 4; ++kk) {
      bf16x8 af[4], bfr[4];
#pragma unroll
      for (int m = 0; m < 4; ++m) af[m] = *(const bf16x8*)&As[wr * 64 + m * 16 + lr][kk * 32 + lkb * 8];
#pragma unroll
      for (int n = 0; n < 4; ++n) bfr[n] = *(const bf16x8*)&Bs[wc * 64 + n * 16 + lr][kk * 32 + lkb * 8];
#pragma unroll
      for (int m = 0; m < 4; ++m)
#pragma unroll
        for (int n = 0; n < 4; ++n)
          acc[m][n] = __builtin_amdgcn_mfma_f32_16x16x32_bf16(af[m], bfr[n], acc[m][n], 0, 0, 0);
    }
    __syncthreads();
  }

  // epilogue 1: h1 = relu(acc + b1) -> As ; stage w2 -> Bs
#pragma unroll
  for (int n = 0; n < 4; ++n) {
    int colg = wc * 64 + n * 16 + lr;
    float bias = b1[colg];
#pragma unroll
    for (int m = 0; m < 4; ++m)
#pragma unroll
      for (int r = 0; r < 4; ++r) {
        int rowg = wr * 64 + m * 16 + lkb * 4 + r;
        float v = acc[m][n][r] + bias;
        v = v > 0.f ? v : 0.f;
        As[rowg][colg] = f2bf(v);
        acc[m][n][r] = 0.f;
      }
  }
  for (int i = tid; i < 128 * 16; i += 256) {
    int r = i >> 4, q = (i & 15) << 3;
    *(u16x8*)&Bs[r][q] = *(const u16x8*)(w2 + (r << 7) + q);
  }
  __syncthreads();

  // layer 2
#pragma unroll
  for (int kk = 0; kk < 4; ++kk) {
    bf16x8 af[4], bfr[4];
#pragma unroll
    for (int m = 0; m < 4; ++m) af[m] = *(const bf16x8*)&As[wr * 64 + m * 16 + lr][kk * 32 + lkb * 8];
#pragma unroll
    for (int n = 0; n < 4; ++n) bfr[n] = *(const bf16x8*)&Bs[wc * 64 + n * 16 + lr][kk * 32 + lkb * 8];
#pragma unroll
    for (int m = 0; m < 4; ++m)
#pragma unroll
      for (int n = 0; n < 4; ++n)
        acc[m][n] = __builtin_amdgcn_mfma_f32_16x16x32_bf16(af[m], bfr[n], acc[m][n], 0, 0, 0);
  }
  __syncthreads();

  // epilogue 2: h2 -> As ; stage w3 -> Bs
#pragma unroll
  for (int n = 0; n < 4; ++n) {
    int colg = wc * 64 + n * 16 + lr;
    float bias = b2[colg];
#pragma unroll
    for (int m = 0; m < 4; ++m)
#pragma unroll
      for (int r = 0; r < 4; ++r) {
        int rowg = wr * 64 + m * 16 + lkb * 4 + r;
        float v = acc[m][n][r] + bias;
        v = v > 0.f ? v : 0.f;
        As[rowg][colg] = f2bf(v);
        acc[m][n][r] = 0.f;
      }
  }
  for (int i = tid; i < 128 * 16; i += 256) {
    int r = i >> 4, q = (i & 15) << 3;
    *(u16x8*)&Bs[r][q] = *(const u16x8*)(w3 + (r << 7) + q);
  }
  __syncthreads();

  // layer 3
#pragma unroll
  for (int kk = 0; kk < 4; ++kk) {
    bf16x8 af[4], bfr[4];
#pragma unroll
    for (int m = 0; m < 4; ++m) af[m] = *(const bf16x8*)&As[wr * 64 + m * 16 + lr][kk * 32 + lkb * 8];
#pragma unroll
    for (int n = 0; n < 4; ++n) bfr[n] = *(const bf16x8*)&Bs[wc * 64 + n * 16 + lr][kk * 32 + lkb * 8];
#pragma unroll
    for (int m = 0; m < 4; ++m)
#pragma unroll
      for (int n = 0; n < 4; ++n)
        acc[m][n] = __builtin_amdgcn_mfma_f32_16x16x32_bf16(af[m], bfr[n], acc[m][n], 0, 0, 0);
  }

  // epilogue 3: edge_out stores + per-graph esum partials (no global scatter atomics)
#pragma unroll
  for (int n = 0; n < 4; ++n) {
    int colg = wc * 64 + n * 16 + lr;
    float bias = b3[colg];
#pragma unroll
    for (int m = 0; m < 4; ++m)
#pragma unroll
      for (int r = 0; r < 4; ++r) {
        int rowg = wr * 64 + m * 16 + lkb * 4 + r;
        float v = acc[m][n][r] + bias;
        edge_out[(size_t)(e0 + rowg) * DD + colg] = v;
        atomicAdd(&red[ebat_s[rowg]][colg], v);
      }
  }
  __syncthreads();
  for (int i = tid; i < NBATCH * 128; i += 256) atomicAdd(&esum[i], (&red[0][0])[i]);
}

// ---------------- Node MLP kernel: tile = 128 nodes, CSR gather for agg ----------------
__global__ __launch_bounds__(256, 2) void node_kernel(
    const u16* __restrict__ xbf, const float* __restrict__ edge_out,
    const int* __restrict__ offs, const int* __restrict__ perm,
    const float* __restrict__ u, const int* __restrict__ batch,
    const u16* __restrict__ w1, const u16* __restrict__ w2, const u16* __restrict__ w3,
    const float* __restrict__ b1, const float* __restrict__ b2, const float* __restrict__ b3,
    float* __restrict__ x_out, float* __restrict__ nsum)
{
  __shared__ u16 As[128][136];
  __shared__ u16 Bs[128][136];
  __shared__ float red[NBATCH][128];
  __shared__ int nbat_s[128];

  const int tid = threadIdx.x;
  const int lane = tid & 63;
  const int wave = tid >> 6;
  const int wr = wave >> 1, wc = wave & 1;
  const int lr = lane & 15;
  const int lkb = lane >> 4;
  const int n0 = blockIdx.x * 128;

  if (tid < 128) {
    int node = n0 + tid;
    nbat_s[tid] = (node < NN) ? batch[node] : 0;
  }
  for (int i = tid; i < NBATCH * 128; i += 256) (&red[0][0])[i] = 0.f;

  f32x4 acc[4][4];
#pragma unroll
  for (int m = 0; m < 4; ++m)
#pragma unroll
    for (int n = 0; n < 4; ++n) { acc[m][n][0]=0.f; acc[m][n][1]=0.f; acc[m][n][2]=0.f; acc[m][n][3]=0.f; }

  __syncthreads();

  // ---- layer 1: K=384, 3 chunks (x | agg(gathered) | u[batch])
  for (int c = 0; c < 3; ++c) {
    // stage weights chunk
    for (int i = tid; i < 128 * 16; i += 256) {
      int r = i >> 4, q = (i & 15) << 3;
      *(u16x8*)&Bs[r][q] = *(const u16x8*)(w1 + (c << 14) + (r << 7) + q);
    }
    if (c != 1) {
      for (int i = tid; i < 128 * 16; i += 256) {
        int r = i >> 4, q = (i & 15) << 3;
        int node = n0 + r;
        u16x8 v;
        if (node >= NN) { v[0]=0;v[1]=0;v[2]=0;v[3]=0;v[4]=0;v[5]=0;v[6]=0;v[7]=0; }
        else if (c == 0) v = *(const u16x8*)(xbf + (size_t)node * DD + q);
        else             v = cvt8(u + (size_t)nbat_s[r] * DD + q);
        *(u16x8*)&As[r][q] = v;
      }
    } else {
      // CSR gather-sum: 16-lane groups, each owns one node-row at a time
      const int g = tid >> 4;
      const int cb = (tid & 15) << 3;
      for (int it = 0; it < 8; ++it) {
        int r = g + (it << 4);
        int node = n0 + r;
        f32x4 a0 = {0.f,0.f,0.f,0.f}, a1 = {0.f,0.f,0.f,0.f};
        if (node < NN) {
          int j0 = offs[node], j1 = offs[node + 1];
          for (int j = j0; j < j1; ++j) {
            int e = perm[j];
            const f32x4* p = (const f32x4*)(edge_out + (size_t)e * DD + cb);
            a0 += p[0]; a1 += p[1];
          }
        }
        u16x8 v;
        v[0]=f2bf(a0[0]); v[1]=f2bf(a0[1]); v[2]=f2bf(a0[2]); v[3]=f2bf(a0[3]);
        v[4]=f2bf(a1[0]); v[5]=f2bf(a1[1]); v[6]=f2bf(a1[2]); v[7]=f2bf(a1[3]);
        *(u16x8*)&As[r][cb] = v;
      }
    }
    __syncthreads();
#pragma unroll
    for (int kk = 0; kk < 4; ++kk) {
      bf16x8 af[4], bfr[4];
#pragma unroll
      for (int m = 0; m < 4; ++m) af[m] = *(const bf16x8*)&As[wr * 64 + m * 16 + lr][kk * 32 + lkb * 8];
#pragma unroll
      for (int n = 0; n < 4; ++n) bfr[n] = *(const bf16x8*)&Bs[wc * 64 + n * 16 + lr][kk * 32 + lkb * 8];
#pragma unroll
      for (int m = 0; m < 4; ++m)
#pragma unroll
        for (int n = 0; n < 4; ++n)
          acc[m][n] = __builtin_amdgcn_mfma_f32_16x16x32_bf16(af[m], bfr[n], acc[m][n], 0, 0, 0);
    }
    __syncthreads();
  }

  // epilogue 1
#pragma unroll
  for (int n = 0; n < 4; ++n) {
    int colg = wc * 64 + n * 16 + lr;
    float bias = b1[colg];
#pragma unroll
    for (int m = 0; m < 4; ++m)
#pragma unroll
      for (int r = 0; r < 4; ++r) {
        int rowg = wr * 64 + m * 16 + lkb * 4 + r;
        float v = acc[m][n][r] + bias;
        v = v > 0.f ? v : 0.f;
        As[rowg][colg] = f2bf(v);
        acc[m][n][r] = 0.f;
      }
  }
  for (int i = tid; i < 128 * 16; i += 256) {
    int r = i >> 4, q = (i & 15) << 3;
    *(u16x8*)&Bs[r][q] = *(const u16x8*)(w2 + (r << 7) + q);
  }
  __syncthreads();

  // layer 2
#pragma unroll
  for (int kk = 0; kk < 4; ++kk) {
    bf16x8 af[4], bfr[4];
#pragma unroll
    for (int m = 0; m < 4; ++m) af[m] = *(const bf16x8*)&As[wr * 64 + m * 16 + lr][kk * 32 + lkb * 8];
#pragma unroll
    for (int n = 0; n < 4; ++n) bfr[n] = *(const bf16x8*)&Bs[wc * 64 + n * 16 + lr][kk * 32 + lkb * 8];
#pragma unroll
    for (int m = 0; m < 4; ++m)
#pragma unroll
      for (int n = 0; n < 4; ++n)
        acc[m][n] = __builtin_amdgcn_mfma_f32_16x16x32_bf16(af[m], bfr[n], acc[m][n], 0, 0, 0);
  }
  __syncthreads();

  // epilogue 2
#pragma unroll
  for (int n = 0; n < 4; ++n) {
    int colg = wc * 64 + n * 16 + lr;
    float bias = b2[colg];
#pragma unroll
    for (int m = 0; m < 4; ++m)
#pragma unroll
      for (int r = 0; r < 4; ++r) {
        int rowg = wr * 64 + m * 16 + lkb * 4 + r;
        float v = acc[m][n][r] + bias;
        v = v > 0.f ? v : 0.f;
        As[rowg][colg] = f2bf(v);
        acc[m][n][r] = 0.f;
      }
  }
  for (int i = tid; i < 128 * 16; i += 256) {
    int r = i >> 4, q = (i & 15) << 3;
    *(u16x8*)&Bs[r][q] = *(const u16x8*)(w3 + (r << 7) + q);
  }
  __syncthreads();

  // layer 3
#pragma unroll
  for (int kk = 0; kk < 4; ++kk) {
    bf16x8 af[4], bfr[4];
#pragma unroll
    for (int m = 0; m < 4; ++m) af[m] = *(const bf16x8*)&As[wr * 64 + m * 16 + lr][kk * 32 + lkb * 8];
#pragma unroll
    for (int n = 0; n < 4; ++n) bfr[n] = *(const bf16x8*)&Bs[wc * 64 + n * 16 + lr][kk * 32 + lkb * 8];
#pragma unroll
    for (int m = 0; m < 4; ++m)
#pragma unroll
      for (int n = 0; n < 4; ++n)
        acc[m][n] = __builtin_amdgcn_mfma_f32_16x16x32_bf16(af[m], bfr[n], acc[m][n], 0, 0, 0);
  }

  // epilogue 3: x_out + node-mean partials
#pragma unroll
  for (int n = 0; n < 4; ++n) {
    int colg = wc * 64 + n * 16 + lr;
    float bias = b3[colg];
#pragma unroll
    for (int m = 0; m < 4; ++m)
#pragma unroll
      for (int r = 0; r < 4; ++r) {
        int rowg = wr * 64 + m * 16 + lkb * 4 + r;
        int node = n0 + rowg;
        if (node < NN) {
          float v = acc[m][n][r] + bias;
          x_out[(size_t)node * DD + colg] = v;
          atomicAdd(&red[nbat_s[rowg]][colg], v);
        }
      }
  }
  __syncthreads();
  for (int i = tid; i < NBATCH * 128; i += 256) atomicAdd(&nsum[i], (&red[0][0])[i]);
}

// ---------------- Global MLP (fp32, tiny) ----------------
__global__ void global_kernel(
    const float* __restrict__ u,
    const float* __restrict__ nsum, const unsigned* __restrict__ ncnt,
    const float* __restrict__ esum, const unsigned* __restrict__ ecnt,
    const float* __restrict__ gW1, const float* __restrict__ gb1,
    const float* __restrict__ gW2, const float* __restrict__ gb2,
    const float* __restrict__ gW3, const float* __restrict__ gb3,
    float* __restrict__ u_out)
{
  __shared__ float gin[NBATCH][384];
  __shared__ float h1[NBATCH][128];
  __shared__ float h2[NBATCH][128];
  int tid = threadIdx.x;
  for (int i = tid; i < NBATCH * 128; i += 256) {
    int r = i >> 7, c = i & 127;
    float nc = (float)(ncnt[r] < 1u ? 1u : ncnt[r]);
    float ec = (float)(ecnt[r] < 1u ? 1u : ecnt[r]);
    gin[r][c] = u[i];
    gin[r][128 + c] = nsum[i] / nc;
    gin[r][256 + c] = esum[i] / ec;
  }
  __syncthreads();
  for (int o = tid; o < NBATCH * 128; o += 256) {
    int r = o >> 7, n = o & 127;
    float s = gb1[n];
    for (int k = 0; k < 384; ++k) s += gin[r][k] * gW1[k * 128 + n];
    h1[r][n] = fmaxf(s, 0.f);
  }
  __syncthreads();
  for (int o = tid; o < NBATCH * 128; o += 256) {
    int r = o >> 7, n = o & 127;
    float s = gb2[n];
    for (int k = 0; k < 128; ++k) s += h1[r][k] * gW2[k * 128 + n];
    h2[r][n] = fmaxf(s, 0.f);
  }
  __syncthreads();
  for (int o = tid; o < NBATCH * 128; o += 256) {
    int r = o >> 7, n = o & 127;
    float s = gb3[n];
    for (int k = 0; k < 128; ++k) s += h2[r][k] * gW3[k * 128 + n];
    u_out[o] = s;
  }
}

extern "C" void kernel_launch(void* const* d_in, const int* in_sizes, int n_in,
                              void* d_out, int out_size, void* d_ws, size_t ws_size,
                              hipStream_t stream) {
  const float* x          = (const float*)d_in[0];
  const int*   edge_index = (const int*)d_in[1];
  const float* edge_attr  = (const float*)d_in[2];
  const float* u          = (const float*)d_in[3];
  const int*   batch      = (const int*)d_in[4];
  const float* eW1 = (const float*)d_in[5];  const float* eb1 = (const float*)d_in[6];
  const float* eW2 = (const float*)d_in[7];  const float* eb2 = (const float*)d_in[8];
  const float* eW3 = (const float*)d_in[9];  const float* eb3 = (const float*)d_in[10];
  const float* nW1 = (const float*)d_in[11]; const float* nb1 = (const float*)d_in[12];
  const float* nW2 = (const float*)d_in[13]; const float* nb2 = (const float*)d_in[14];
  const float* nW3 = (const float*)d_in[15]; const float* nb3 = (const float*)d_in[16];
  const float* gW1 = (const float*)d_in[17]; const float* gb1 = (const float*)d_in[18];
  const float* gW2 = (const float*)d_in[19]; const float* gb2 = (const float*)d_in[20];
  const float* gW3 = (const float*)d_in[21]; const float* gb3 = (const float*)d_in[22];

  float* out      = (float*)d_out;
  float* x_out    = out;                                  // [NN][128]
  float* edge_out = out + (size_t)NN * DD;                // [NE][128]
  float* u_out    = out + (size_t)(NN + NE) * DD;         // [8][128]

  char* ws = (char*)d_ws;
  u16* wE1t = (u16*)(ws + 0);         // 131072
  u16* wE2t = (u16*)(ws + 131072);    // 32768
  u16* wE3t = (u16*)(ws + 163840);    // 32768
  u16* wN1t = (u16*)(ws + 196608);    // 98304
  u16* wN2t = (u16*)(ws + 294912);    // 32768
  u16* wN3t = (u16*)(ws + 327680);    // 32768
  float*    esum = (float*)(ws + 360448);     // 4096
  float*    nsum = (float*)(ws + 364544);     // 4096
  unsigned* ecnt = (unsigned*)(ws + 368640);  // 32
  unsigned* ncnt = (unsigned*)(ws + 368672);  // 32
  int*      bsum = (int*)(ws + 368704);       // 49*4 -> pad to 960
  int*      cnt  = (int*)(ws + 369664);       // 50000*4 = 200000
  int*      offs = (int*)(ws + 569664);       // 50001*4 = 200004
  int*      cursor = (int*)(ws + 769696);     // 200000
  int*      perm = (int*)(ws + 969696);       // 400000*4 = 1600000
  u16*      xbf  = (u16*)(ws + 2569728);      // 12800000 -> ends 15369728

  // zero per-launch accumulators: esum..cnt region [360448, 569664)
  hipMemsetAsync(ws + 360448, 0, 569664 - 360448, stream);

  wconv_kernel<<<256, 256, 0, stream>>>(eW1, wE1t, 512);
  wconv_kernel<<<64, 256, 0, stream>>>(eW2, wE2t, 128);
  wconv_kernel<<<64, 256, 0, stream>>>(eW3, wE3t, 128);
  wconv_kernel<<<192, 256, 0, stream>>>(nW1, wN1t, 384);
  wconv_kernel<<<64, 256, 0, stream>>>(nW2, wN2t, 128);
  wconv_kernel<<<64, 256, 0, stream>>>(nW3, wN3t, 128);
  xconv_kernel<<<6250, 256, 0, stream>>>(x, xbf, NN * DD / 4);

  // CSR prep
  ehist_kernel<<<(NE + 255) / 256, 256, 0, stream>>>(edge_index, batch, cnt, ecnt);
  nhist_kernel<<<(NN + 255) / 256, 256, 0, stream>>>(batch, ncnt);
  scan1_kernel<<<(NN + SCAN_BLK - 1) / SCAN_BLK, 256, 0, stream>>>(cnt, offs, bsum, NN);
  scan2_kernel<<<1, 64, 0, stream>>>(bsum, (NN + SCAN_BLK - 1) / SCAN_BLK);
  scan3_kernel<<<(NN + 255) / 256, 256, 0, stream>>>(offs, cursor, bsum, NN, NE);
  scatter_kernel<<<(NE + 255) / 256, 256, 0, stream>>>(edge_index, cursor, perm);

  edge_kernel<<<NE / 128, 256, 0, stream>>>(
      xbf, edge_attr, u, edge_index, batch,
      wE1t, wE2t, wE3t, eb1, eb2, eb3,
      edge_out, esum);

  node_kernel<<<(NN + 127) / 128, 256, 0, stream>>>(
      xbf, edge_out, offs, perm, u, batch,
      wN1t, wN2t, wN3t, nb1, nb2, nb3,
      x_out, nsum);

  global_kernel<<<1, 256, 0, stream>>>(
      u, nsum, ncnt, esum, ecnt,
      gW1, gb1, gW2, gb2, gW3, gb3, u_out);
}

// Round 3
// 689.044 us; speedup vs baseline: 1.1075x; 1.1075x over previous
//
#include <hip/hip_runtime.h>

#define NN 50000
#define NE 400000
#define NBATCH 8
#define DD 128

typedef unsigned short u16;
typedef __attribute__((ext_vector_type(8))) short bf16x8;
typedef __attribute__((ext_vector_type(8))) unsigned short u16x8;
typedef __attribute__((ext_vector_type(4))) unsigned short u16x4;
typedef __attribute__((ext_vector_type(4))) float f32x4;

__device__ __forceinline__ u16 f2bf(float f) {
  union { float f; unsigned u; } a; a.f = f;
  unsigned r = a.u + 0x7fffu + ((a.u >> 16) & 1u);
  return (u16)(r >> 16);
}

__device__ __forceinline__ bf16x8 cvt8(const float* p) {
  f32x4 a = *(const f32x4*)p;
  f32x4 b = *(const f32x4*)(p + 4);
  u16x8 r;
  r[0]=f2bf(a[0]); r[1]=f2bf(a[1]); r[2]=f2bf(a[2]); r[3]=f2bf(a[3]);
  r[4]=f2bf(b[0]); r[5]=f2bf(b[1]); r[6]=f2bf(b[2]); r[7]=f2bf(b[3]);
  union { u16x8 u; bf16x8 b; } c; c.u = r;
  return c.b;
}

// Convert+transpose fp32 weight [K][128] -> bf16 chunked [K/128][128 n][128 k]
__global__ void wconv_kernel(const float* __restrict__ src, u16* __restrict__ dst, int K) {
  int idx = blockIdx.x * 256 + threadIdx.x;
  if (idx >= K * 128) return;
  int k = idx >> 7, n = idx & 127;
  dst[((k >> 7) << 14) + (n << 7) + (k & 127)] = f2bf(src[idx]);
}

__global__ void xconv_kernel(const float* __restrict__ x, u16* __restrict__ xbf, int total4) {
  int i = blockIdx.x * 256 + threadIdx.x;
  if (i >= total4) return;
  f32x4 v = ((const f32x4*)x)[i];
  u16x4 o; o[0]=f2bf(v[0]); o[1]=f2bf(v[1]); o[2]=f2bf(v[2]); o[3]=f2bf(v[3]);
  ((u16x4*)xbf)[i] = o;
}

// ---------------- Edge MLP kernel: tile = 128 edges, direct-fragment loads ----------------
__global__ __launch_bounds__(256, 3) void edge_kernel(
    const u16* __restrict__ xbf, const float* __restrict__ edge_attr,
    const float* __restrict__ u, const int* __restrict__ edge_index,
    const int* __restrict__ batch,
    const u16* __restrict__ w1, const u16* __restrict__ w2, const u16* __restrict__ w3,
    const float* __restrict__ b1, const float* __restrict__ b2, const float* __restrict__ b3,
    float* __restrict__ edge_out, float* agg,
    float* __restrict__ esum, unsigned* __restrict__ ecnt)
{
  __shared__ u16 Hs[128][136];
  __shared__ float red[NBATCH][128];
  __shared__ int rows_s[128], cols_s[128], ebat_s[128];
  __shared__ unsigned cnt8[NBATCH];

  const int tid = threadIdx.x;
  const int lane = tid & 63;
  const int wave = tid >> 6;
  const int wr = wave >> 1, wc = wave & 1;
  const int lr = lane & 15;
  const int lkb = lane >> 4;
  const int e0 = blockIdx.x * 128;

  if (tid < 128) {
    int r = edge_index[e0 + tid];
    int c = edge_index[NE + e0 + tid];
    rows_s[tid] = r; cols_s[tid] = c;
    ebat_s[tid] = batch[r];
  }
  for (int i = tid; i < NBATCH * 128; i += 256) (&red[0][0])[i] = 0.f;
  if (tid < NBATCH) cnt8[tid] = 0;

  f32x4 acc[4][4];
#pragma unroll
  for (int m = 0; m < 4; ++m)
#pragma unroll
    for (int n = 0; n < 4; ++n) { acc[m][n][0]=0.f; acc[m][n][1]=0.f; acc[m][n][2]=0.f; acc[m][n][3]=0.f; }

  __syncthreads();

  int xr[4], cr[4], br[4], er[4];
#pragma unroll
  for (int m = 0; m < 4; ++m) {
    int r = wr * 64 + m * 16 + lr;
    xr[m] = rows_s[r]; cr[m] = cols_s[r]; br[m] = ebat_s[r]; er[m] = e0 + r;
  }
  const int bcol = wc * 64 + lr;  // base B row index (output col) for n=0

  // ---- layer 1: K=512, direct fragment gathers, NO barriers
#pragma unroll
  for (int c = 0; c < 4; ++c) {
    const u16* wsrc = w1 + (c << 14);
#pragma unroll
    for (int kk = 0; kk < 4; ++kk) {
      const int k0 = kk * 32 + lkb * 8;
      bf16x8 af[4], bf[4];
#pragma unroll
      for (int m = 0; m < 4; ++m) {
        if (c == 0)      af[m] = *(const bf16x8*)(xbf + (size_t)xr[m] * DD + k0);
        else if (c == 1) af[m] = *(const bf16x8*)(xbf + (size_t)cr[m] * DD + k0);
        else if (c == 2) af[m] = cvt8(edge_attr + (size_t)er[m] * DD + k0);
        else             af[m] = cvt8(u + (size_t)br[m] * DD + k0);
      }
#pragma unroll
      for (int n = 0; n < 4; ++n)
        bf[n] = *(const bf16x8*)(wsrc + ((bcol + n * 16) << 7) + k0);
#pragma unroll
      for (int m = 0; m < 4; ++m)
#pragma unroll
        for (int n = 0; n < 4; ++n)
          acc[m][n] = __builtin_amdgcn_mfma_f32_16x16x32_bf16(af[m], bf[n], acc[m][n], 0, 0, 0);
    }
  }

  // epilogue 1: h1 = relu(acc + b1) -> Hs
#pragma unroll
  for (int n = 0; n < 4; ++n) {
    int colg = wc * 64 + n * 16 + lr;
    float bias = b1[colg];
#pragma unroll
    for (int m = 0; m < 4; ++m)
#pragma unroll
      for (int r = 0; r < 4; ++r) {
        int rowg = wr * 64 + m * 16 + lkb * 4 + r;
        float v = acc[m][n][r] + bias;
        v = v > 0.f ? v : 0.f;
        Hs[rowg][colg] = f2bf(v);
        acc[m][n][r] = 0.f;
      }
  }
  __syncthreads();

  // layer 2: A from Hs, B direct
#pragma unroll
  for (int kk = 0; kk < 4; ++kk) {
    const int k0 = kk * 32 + lkb * 8;
    bf16x8 af[4], bf[4];
#pragma unroll
    for (int m = 0; m < 4; ++m) af[m] = *(const bf16x8*)&Hs[wr * 64 + m * 16 + lr][k0];
#pragma unroll
    for (int n = 0; n < 4; ++n) bf[n] = *(const bf16x8*)(w2 + ((bcol + n * 16) << 7) + k0);
#pragma unroll
    for (int m = 0; m < 4; ++m)
#pragma unroll
      for (int n = 0; n < 4; ++n)
        acc[m][n] = __builtin_amdgcn_mfma_f32_16x16x32_bf16(af[m], bf[n], acc[m][n], 0, 0, 0);
  }
  __syncthreads();

  // epilogue 2: h2 -> Hs
#pragma unroll
  for (int n = 0; n < 4; ++n) {
    int colg = wc * 64 + n * 16 + lr;
    float bias = b2[colg];
#pragma unroll
    for (int m = 0; m < 4; ++m)
#pragma unroll
      for (int r = 0; r < 4; ++r) {
        int rowg = wr * 64 + m * 16 + lkb * 4 + r;
        float v = acc[m][n][r] + bias;
        v = v > 0.f ? v : 0.f;
        Hs[rowg][colg] = f2bf(v);
        acc[m][n][r] = 0.f;
      }
  }
  __syncthreads();

  // layer 3
#pragma unroll
  for (int kk = 0; kk < 4; ++kk) {
    const int k0 = kk * 32 + lkb * 8;
    bf16x8 af[4], bf[4];
#pragma unroll
    for (int m = 0; m < 4; ++m) af[m] = *(const bf16x8*)&Hs[wr * 64 + m * 16 + lr][k0];
#pragma unroll
    for (int n = 0; n < 4; ++n) bf[n] = *(const bf16x8*)(w3 + ((bcol + n * 16) << 7) + k0);
#pragma unroll
    for (int m = 0; m < 4; ++m)
#pragma unroll
      for (int n = 0; n < 4; ++n)
        acc[m][n] = __builtin_amdgcn_mfma_f32_16x16x32_bf16(af[m], bf[n], acc[m][n], 0, 0, 0);
  }

  // epilogue 3: edge_out + scatter-add agg + per-graph esum partials
#pragma unroll
  for (int n = 0; n < 4; ++n) {
    int colg = wc * 64 + n * 16 + lr;
    float bias = b3[colg];
#pragma unroll
    for (int m = 0; m < 4; ++m)
#pragma unroll
      for (int r = 0; r < 4; ++r) {
        int rowg = wr * 64 + m * 16 + lkb * 4 + r;
        float v = acc[m][n][r] + bias;
        edge_out[(size_t)(e0 + rowg) * DD + colg] = v;
        atomicAdd(&agg[(size_t)cols_s[rowg] * DD + colg], v);
        atomicAdd(&red[ebat_s[rowg]][colg], v);
      }
  }
  if (tid < 128) atomicAdd(&cnt8[ebat_s[tid]], 1u);
  __syncthreads();
  for (int i = tid; i < NBATCH * 128; i += 256) atomicAdd(&esum[i], (&red[0][0])[i]);
  if (tid < NBATCH) atomicAdd(&ecnt[tid], cnt8[tid]);
}

// ---------------- Node MLP kernel: tile = 128 nodes, direct-fragment loads ----------------
__global__ __launch_bounds__(256, 3) void node_kernel(
    const u16* __restrict__ xbf, float* aggx /* agg in, x_out out (same region) */,
    const float* __restrict__ u, const int* __restrict__ batch,
    const u16* __restrict__ w1, const u16* __restrict__ w2, const u16* __restrict__ w3,
    const float* __restrict__ b1, const float* __restrict__ b2, const float* __restrict__ b3,
    float* __restrict__ nsum, unsigned* __restrict__ ncnt)
{
  __shared__ u16 Hs[128][136];
  __shared__ float red[NBATCH][128];
  __shared__ int nbat_s[128];
  __shared__ unsigned cnt8[NBATCH];

  const int tid = threadIdx.x;
  const int lane = tid & 63;
  const int wave = tid >> 6;
  const int wr = wave >> 1, wc = wave & 1;
  const int lr = lane & 15;
  const int lkb = lane >> 4;
  const int n0 = blockIdx.x * 128;

  if (tid < 128) {
    int node = n0 + tid;
    nbat_s[tid] = (node < NN) ? batch[node] : 0;
  }
  for (int i = tid; i < NBATCH * 128; i += 256) (&red[0][0])[i] = 0.f;
  if (tid < NBATCH) cnt8[tid] = 0;

  f32x4 acc[4][4];
#pragma unroll
  for (int m = 0; m < 4; ++m)
#pragma unroll
    for (int n = 0; n < 4; ++n) { acc[m][n][0]=0.f; acc[m][n][1]=0.f; acc[m][n][2]=0.f; acc[m][n][3]=0.f; }

  __syncthreads();

  int nd[4], nb[4], ok[4];
#pragma unroll
  for (int m = 0; m < 4; ++m) {
    int r = wr * 64 + m * 16 + lr;
    nd[m] = n0 + r;
    ok[m] = nd[m] < NN;
    nb[m] = nbat_s[r];
  }
  const int bcol = wc * 64 + lr;
  const bf16x8 zero8 = {};

  // ---- layer 1: K=384, direct fragment gathers
#pragma unroll
  for (int c = 0; c < 3; ++c) {
    const u16* wsrc = w1 + (c << 14);
#pragma unroll
    for (int kk = 0; kk < 4; ++kk) {
      const int k0 = kk * 32 + lkb * 8;
      bf16x8 af[4], bf[4];
#pragma unroll
      for (int m = 0; m < 4; ++m) {
        if (!ok[m])      af[m] = zero8;
        else if (c == 0) af[m] = *(const bf16x8*)(xbf + (size_t)nd[m] * DD + k0);
        else if (c == 1) af[m] = cvt8(aggx + (size_t)nd[m] * DD + k0);
        else             af[m] = cvt8(u + (size_t)nb[m] * DD + k0);
      }
#pragma unroll
      for (int n = 0; n < 4; ++n)
        bf[n] = *(const bf16x8*)(wsrc + ((bcol + n * 16) << 7) + k0);
#pragma unroll
      for (int m = 0; m < 4; ++m)
#pragma unroll
        for (int n = 0; n < 4; ++n)
          acc[m][n] = __builtin_amdgcn_mfma_f32_16x16x32_bf16(af[m], bf[n], acc[m][n], 0, 0, 0);
    }
  }

  // epilogue 1
#pragma unroll
  for (int n = 0; n < 4; ++n) {
    int colg = wc * 64 + n * 16 + lr;
    float bias = b1[colg];
#pragma unroll
    for (int m = 0; m < 4; ++m)
#pragma unroll
      for (int r = 0; r < 4; ++r) {
        int rowg = wr * 64 + m * 16 + lkb * 4 + r;
        float v = acc[m][n][r] + bias;
        v = v > 0.f ? v : 0.f;
        Hs[rowg][colg] = f2bf(v);
        acc[m][n][r] = 0.f;
      }
  }
  __syncthreads();

  // layer 2
#pragma unroll
  for (int kk = 0; kk < 4; ++kk) {
    const int k0 = kk * 32 + lkb * 8;
    bf16x8 af[4], bf[4];
#pragma unroll
    for (int m = 0; m < 4; ++m) af[m] = *(const bf16x8*)&Hs[wr * 64 + m * 16 + lr][k0];
#pragma unroll
    for (int n = 0; n < 4; ++n) bf[n] = *(const bf16x8*)(w2 + ((bcol + n * 16) << 7) + k0);
#pragma unroll
    for (int m = 0; m < 4; ++m)
#pragma unroll
      for (int n = 0; n < 4; ++n)
        acc[m][n] = __builtin_amdgcn_mfma_f32_16x16x32_bf16(af[m], bf[n], acc[m][n], 0, 0, 0);
  }
  __syncthreads();

  // epilogue 2
#pragma unroll
  for (int n = 0; n < 4; ++n) {
    int colg = wc * 64 + n * 16 + lr;
    float bias = b2[colg];
#pragma unroll
    for (int m = 0; m < 4; ++m)
#pragma unroll
      for (int r = 0; r < 4; ++r) {
        int rowg = wr * 64 + m * 16 + lkb * 4 + r;
        float v = acc[m][n][r] + bias;
        v = v > 0.f ? v : 0.f;
        Hs[rowg][colg] = f2bf(v);
        acc[m][n][r] = 0.f;
      }
  }
  __syncthreads();

  // layer 3
#pragma unroll
  for (int kk = 0; kk < 4; ++kk) {
    const int k0 = kk * 32 + lkb * 8;
    bf16x8 af[4], bf[4];
#pragma unroll
    for (int m = 0; m < 4; ++m) af[m] = *(const bf16x8*)&Hs[wr * 64 + m * 16 + lr][k0];
#pragma unroll
    for (int n = 0; n < 4; ++n) bf[n] = *(const bf16x8*)(w3 + ((bcol + n * 16) << 7) + k0);
#pragma unroll
    for (int m = 0; m < 4; ++m)
#pragma unroll
      for (int n = 0; n < 4; ++n)
        acc[m][n] = __builtin_amdgcn_mfma_f32_16x16x32_bf16(af[m], bf[n], acc[m][n], 0, 0, 0);
  }

  // epilogue 3: x_out overwrites agg rows of this block; node-mean partials
#pragma unroll
  for (int n = 0; n < 4; ++n) {
    int colg = wc * 64 + n * 16 + lr;
    float bias = b3[colg];
#pragma unroll
    for (int m = 0; m < 4; ++m)
#pragma unroll
      for (int r = 0; r < 4; ++r) {
        int rowg = wr * 64 + m * 16 + lkb * 4 + r;
        int node = n0 + rowg;
        if (node < NN) {
          float v = acc[m][n][r] + bias;
          aggx[(size_t)node * DD + colg] = v;
          atomicAdd(&red[nbat_s[rowg]][colg], v);
        }
      }
  }
  if (tid < 128 && (n0 + tid) < NN) atomicAdd(&cnt8[nbat_s[tid]], 1u);
  __syncthreads();
  for (int i = tid; i < NBATCH * 128; i += 256) atomicAdd(&nsum[i], (&red[0][0])[i]);
  if (tid < NBATCH) atomicAdd(&ncnt[tid], cnt8[tid]);
}

// ---------------- Global MLP (fp32, tiny) ----------------
__global__ void global_kernel(
    const float* __restrict__ u,
    const float* __restrict__ nsum, const unsigned* __restrict__ ncnt,
    const float* __restrict__ esum, const unsigned* __restrict__ ecnt,
    const float* __restrict__ gW1, const float* __restrict__ gb1,
    const float* __restrict__ gW2, const float* __restrict__ gb2,
    const float* __restrict__ gW3, const float* __restrict__ gb3,
    float* __restrict__ u_out)
{
  __shared__ float gin[NBATCH][384];
  __shared__ float h1[NBATCH][128];
  __shared__ float h2[NBATCH][128];
  int tid = threadIdx.x;
  for (int i = tid; i < NBATCH * 128; i += 256) {
    int r = i >> 7, c = i & 127;
    float nc = (float)(ncnt[r] < 1u ? 1u : ncnt[r]);
    float ec = (float)(ecnt[r] < 1u ? 1u : ecnt[r]);
    gin[r][c] = u[i];
    gin[r][128 + c] = nsum[i] / nc;
    gin[r][256 + c] = esum[i] / ec;
  }
  __syncthreads();
  for (int o = tid; o < NBATCH * 128; o += 256) {
    int r = o >> 7, n = o & 127;
    float s = gb1[n];
    for (int k = 0; k < 384; ++k) s += gin[r][k] * gW1[k * 128 + n];
    h1[r][n] = fmaxf(s, 0.f);
  }
  __syncthreads();
  for (int o = tid; o < NBATCH * 128; o += 256) {
    int r = o >> 7, n = o & 127;
    float s = gb2[n];
    for (int k = 0; k < 128; ++k) s += h1[r][k] * gW2[k * 128 + n];
    h2[r][n] = fmaxf(s, 0.f);
  }
  __syncthreads();
  for (int o = tid; o < NBATCH * 128; o += 256) {
    int r = o >> 7, n = o & 127;
    float s = gb3[n];
    for (int k = 0; k < 128; ++k) s += h2[r][k] * gW3[k * 128 + n];
    u_out[o] = s;
  }
}

extern "C" void kernel_launch(void* const* d_in, const int* in_sizes, int n_in,
                              void* d_out, int out_size, void* d_ws, size_t ws_size,
                              hipStream_t stream) {
  const float* x          = (const float*)d_in[0];
  const int*   edge_index = (const int*)d_in[1];
  const float* edge_attr  = (const float*)d_in[2];
  const float* u          = (const float*)d_in[3];
  const int*   batch      = (const int*)d_in[4];
  const float* eW1 = (const float*)d_in[5];  const float* eb1 = (const float*)d_in[6];
  const float* eW2 = (const float*)d_in[7];  const float* eb2 = (const float*)d_in[8];
  const float* eW3 = (const float*)d_in[9];  const float* eb3 = (const float*)d_in[10];
  const float* nW1 = (const float*)d_in[11]; const float* nb1 = (const float*)d_in[12];
  const float* nW2 = (const float*)d_in[13]; const float* nb2 = (const float*)d_in[14];
  const float* nW3 = (const float*)d_in[15]; const float* nb3 = (const float*)d_in[16];
  const float* gW1 = (const float*)d_in[17]; const float* gb1 = (const float*)d_in[18];
  const float* gW2 = (const float*)d_in[19]; const float* gb2 = (const float*)d_in[20];
  const float* gW3 = (const float*)d_in[21]; const float* gb3 = (const float*)d_in[22];

  float* out      = (float*)d_out;
  float* xout_agg = out;                                  // [NN][128]: agg then x_out
  float* edge_out = out + (size_t)NN * DD;                // [NE][128]
  float* u_out    = out + (size_t)(NN + NE) * DD;         // [8][128]

  char* ws = (char*)d_ws;
  u16* wE1t = (u16*)(ws + 0);         // 131072
  u16* wE2t = (u16*)(ws + 131072);    // 32768
  u16* wE3t = (u16*)(ws + 163840);    // 32768
  u16* wN1t = (u16*)(ws + 196608);    // 98304
  u16* wN2t = (u16*)(ws + 294912);    // 32768
  u16* wN3t = (u16*)(ws + 327680);    // 32768
  float*    esum = (float*)(ws + 360448);     // 4096
  float*    nsum = (float*)(ws + 364544);     // 4096
  unsigned* ecnt = (unsigned*)(ws + 368640);  // 32
  unsigned* ncnt = (unsigned*)(ws + 368672);  // 32
  u16*      xbf  = (u16*)(ws + 393216);       // 12800000

  // zero agg region (x_out part of d_out) and stat accumulators — every launch
  hipMemsetAsync(d_out, 0, (size_t)NN * DD * sizeof(float), stream);
  hipMemsetAsync(ws + 360448, 0, 8288, stream);

  wconv_kernel<<<256, 256, 0, stream>>>(eW1, wE1t, 512);
  wconv_kernel<<<64, 256, 0, stream>>>(eW2, wE2t, 128);
  wconv_kernel<<<64, 256, 0, stream>>>(eW3, wE3t, 128);
  wconv_kernel<<<192, 256, 0, stream>>>(nW1, wN1t, 384);
  wconv_kernel<<<64, 256, 0, stream>>>(nW2, wN2t, 128);
  wconv_kernel<<<64, 256, 0, stream>>>(nW3, wN3t, 128);
  xconv_kernel<<<6250, 256, 0, stream>>>(x, xbf, NN * DD / 4);

  edge_kernel<<<NE / 128, 256, 0, stream>>>(
      xbf, edge_attr, u, edge_index, batch,
      wE1t, wE2t, wE3t, eb1, eb2, eb3,
      edge_out, xout_agg, esum, ecnt);

  node_kernel<<<(NN + 127) / 128, 256, 0, stream>>>(
      xbf, xout_agg, u, batch,
      wN1t, wN2t, wN3t, nb1, nb2, nb3,
      nsum, ncnt);

  global_kernel<<<1, 256, 0, stream>>>(
      u, nsum, ncnt, esum, ecnt,
      gW1, gb1, gW2, gb2, gW3, gb3, u_out);
}

// Round 4
// 647.917 us; speedup vs baseline: 1.1778x; 1.0635x over previous
//
#include <hip/hip_runtime.h>

#define NN 50000
#define NE 400000
#define NBATCH 8
#define DD 128

typedef unsigned short u16;
typedef __attribute__((ext_vector_type(8))) short bf16x8;
typedef __attribute__((ext_vector_type(8))) unsigned short u16x8;
typedef __attribute__((ext_vector_type(4))) unsigned short u16x4;
typedef __attribute__((ext_vector_type(4))) float f32x4;

__device__ __forceinline__ u16 f2bf(float f) {
  union { float f; unsigned u; } a; a.f = f;
  unsigned r = a.u + 0x7fffu + ((a.u >> 16) & 1u);
  return (u16)(r >> 16);
}

__device__ __forceinline__ void glds16(const void* g, void* l) {
  __builtin_amdgcn_global_load_lds(
      (const __attribute__((address_space(1))) unsigned*)g,
      (__attribute__((address_space(3))) unsigned*)l, 16, 0, 0);
}

// Convert+transpose fp32 weight [K][128] -> bf16 chunked [K/128][128 n][128 k]
__global__ void wconv_kernel(const float* __restrict__ src, u16* __restrict__ dst, int K) {
  int idx = blockIdx.x * 256 + threadIdx.x;
  if (idx >= K * 128) return;
  int k = idx >> 7, n = idx & 127;
  dst[((k >> 7) << 14) + (n << 7) + (k & 127)] = f2bf(src[idx]);
}

// fp32 -> bf16 flat copy
__global__ void xconv_kernel(const float* __restrict__ x, u16* __restrict__ xbf, int total4) {
  int i = blockIdx.x * 256 + threadIdx.x;
  if (i >= total4) return;
  f32x4 v = ((const f32x4*)x)[i];
  u16x4 o; o[0]=f2bf(v[0]); o[1]=f2bf(v[1]); o[2]=f2bf(v[2]); o[3]=f2bf(v[3]);
  ((u16x4*)xbf)[i] = o;
}

// ---------------- Edge MLP: 2-phase pipelined, glds-staged ----------------
__global__ __launch_bounds__(256, 2) void edge_kernel(
    const u16* __restrict__ xbf, const u16* __restrict__ eabf /*may be null*/,
    const float* __restrict__ ea_f32, const u16* __restrict__ ubf,
    const int* __restrict__ edge_index, const int* __restrict__ batch,
    const u16* __restrict__ w1, const u16* __restrict__ w2, const u16* __restrict__ w3,
    const float* __restrict__ b1, const float* __restrict__ b2, const float* __restrict__ b3,
    float* __restrict__ edge_out, float* agg,
    float* __restrict__ esum, unsigned* __restrict__ ecnt)
{
  __shared__ u16 As[2][128 * 128];      // 64 KB double buffer (swizzled st)
  __shared__ float red[NBATCH][128];
  __shared__ int rows_s[128], cols_s[128], ebat_s[128];
  __shared__ unsigned cnt8[NBATCH];

  const int tid  = threadIdx.x;
  const int lane = tid & 63;
  const int wave = tid >> 6;
  const int wr = wave >> 1, wc = wave & 1;
  const int lr  = lane & 15;
  const int lkb = lane >> 4;
  const int e0  = blockIdx.x * 128;
  const int bcol = wc * 64 + lr;

  if (tid < 128) {
    int r = edge_index[e0 + tid];
    int c = edge_index[NE + e0 + tid];
    rows_s[tid] = r; cols_s[tid] = c;
    ebat_s[tid] = batch[r];
  }
  for (int i = tid; i < NBATCH * 128; i += 256) (&red[0][0])[i] = 0.f;
  if (tid < NBATCH) cnt8[tid] = 0;

  f32x4 acc[4][4];
#pragma unroll
  for (int m = 0; m < 4; ++m)
#pragma unroll
    for (int n = 0; n < 4; ++n) { acc[m][n][0]=0.f; acc[m][n][1]=0.f; acc[m][n][2]=0.f; acc[m][n][3]=0.f; }

  __syncthreads();  // indices visible

  // stage chunk `c` into buffer `buf` (bf16 sources via global_load_lds)
  auto stage = [&](int buf, int c) {
    if (c == 2 && eabf == nullptr) {
      // fp32 fallback: reg-stage + cvt + swizzled ds_write
#pragma unroll
      for (int j = 0; j < 8; ++j) {
        int t = j * 64 + lane;
        int rr = wave * 32 + (t >> 4);
        int k  = t & 15;                       // 16B slot within row
        const float* p = ea_f32 + (size_t)(e0 + rr) * DD + k * 8;
        f32x4 a = *(const f32x4*)p;
        f32x4 b = *(const f32x4*)(p + 4);
        u16x8 v;
        v[0]=f2bf(a[0]); v[1]=f2bf(a[1]); v[2]=f2bf(a[2]); v[3]=f2bf(a[3]);
        v[4]=f2bf(b[0]); v[5]=f2bf(b[1]); v[6]=f2bf(b[2]); v[7]=f2bf(b[3]);
        *(u16x8*)&As[buf][rr * 128 + ((k ^ (rr & 7)) << 3)] = v;
      }
      return;
    }
#pragma unroll
    for (int i = 0; i < 8; ++i) {
      int rr = wave * 32 + i * 4 + (lane >> 4);
      const u16* rp;
      if (c == 0)      rp = xbf + (size_t)rows_s[rr] * DD;
      else if (c == 1) rp = xbf + (size_t)cols_s[rr] * DD;
      else if (c == 2) rp = eabf + (size_t)(e0 + rr) * DD;
      else             rp = ubf + (size_t)ebat_s[rr] * DD;
      int sd = lane & 15;
      const u16* src = rp + ((sd ^ (rr & 7)) << 3);   // inverse-swizzled source
      u16* dst = &As[buf][(wave * 32 + i * 4) * 128]; // linear wave-uniform dest
      glds16(src, dst);
    }
  };

  auto compute = [&](const u16* AsBuf, const u16* wsrc) {
#pragma unroll
    for (int kk = 0; kk < 4; ++kk) {
      const int k0 = kk * 32 + lkb * 8;
      bf16x8 af[4], bfv[4];
#pragma unroll
      for (int m = 0; m < 4; ++m) {
        int g = wr * 64 + m * 16 + lr;
        int slot = kk * 4 + lkb;
        af[m] = *(const bf16x8*)(AsBuf + g * 128 + ((slot ^ (g & 7)) << 3));
      }
#pragma unroll
      for (int n = 0; n < 4; ++n)
        bfv[n] = *(const bf16x8*)(wsrc + ((bcol + n * 16) << 7) + k0);
#pragma unroll
      for (int m = 0; m < 4; ++m)
#pragma unroll
        for (int n = 0; n < 4; ++n)
          acc[m][n] = __builtin_amdgcn_mfma_f32_16x16x32_bf16(af[m], bfv[n], acc[m][n], 0, 0, 0);
    }
  };

  auto epi_relu = [&](u16* HsBuf, const float* bias) {
#pragma unroll
    for (int n = 0; n < 4; ++n) {
      int colg = wc * 64 + n * 16 + lr;
      float bv = bias[colg];
      int slot = colg >> 3;
#pragma unroll
      for (int m = 0; m < 4; ++m)
#pragma unroll
        for (int r = 0; r < 4; ++r) {
          int rowg = wr * 64 + m * 16 + lkb * 4 + r;
          float v = fmaxf(acc[m][n][r] + bv, 0.f);
          HsBuf[rowg * 128 + ((slot ^ (rowg & 7)) << 3) + (colg & 7)] = f2bf(v);
          acc[m][n][r] = 0.f;
        }
    }
  };

  // ---- layer 1: 4 chunks, 2-phase pipeline
  stage(0, 0);
  __syncthreads();                       // drain c0
  stage(1, 1); compute(As[0], w1);                __syncthreads();  // c0; c1 in flight
  stage(0, 2); compute(As[1], w1 + (1 << 14));    __syncthreads();
  stage(1, 3); compute(As[0], w1 + (2 << 14));    __syncthreads();
               compute(As[1], w1 + (3 << 14));
  // epilogue 1 -> Hs in buffer 0
  epi_relu(As[0], b1);
  __syncthreads();
  // layer 2
  compute(As[0], w2);
  __syncthreads();
  epi_relu(As[1], b2);
  __syncthreads();
  // layer 3
  compute(As[1], w3);

  // epilogue 3: edge_out + agg scatter atomics + per-graph esum partials
#pragma unroll
  for (int n = 0; n < 4; ++n) {
    int colg = wc * 64 + n * 16 + lr;
    float bias = b3[colg];
#pragma unroll
    for (int m = 0; m < 4; ++m)
#pragma unroll
      for (int r = 0; r < 4; ++r) {
        int rowg = wr * 64 + m * 16 + lkb * 4 + r;
        float v = acc[m][n][r] + bias;
        edge_out[(size_t)(e0 + rowg) * DD + colg] = v;
        atomicAdd(&agg[(size_t)cols_s[rowg] * DD + colg], v);
        atomicAdd(&red[ebat_s[rowg]][colg], v);
      }
  }
  if (tid < 128) atomicAdd(&cnt8[ebat_s[tid]], 1u);
  __syncthreads();
  for (int i = tid; i < NBATCH * 128; i += 256) atomicAdd(&esum[i], (&red[0][0])[i]);
  if (tid < NBATCH) atomicAdd(&ecnt[tid], cnt8[tid]);
}

// ---------------- Node MLP: 2-phase pipelined ----------------
__global__ __launch_bounds__(256, 2) void node_kernel(
    const u16* __restrict__ xbf, float* aggx /* agg in, x_out out */,
    const u16* __restrict__ ubf, const int* __restrict__ batch,
    const u16* __restrict__ w1, const u16* __restrict__ w2, const u16* __restrict__ w3,
    const float* __restrict__ b1, const float* __restrict__ b2, const float* __restrict__ b3,
    float* __restrict__ nsum, unsigned* __restrict__ ncnt)
{
  __shared__ u16 As[2][128 * 128];
  __shared__ float red[NBATCH][128];
  __shared__ int nbat_s[128];
  __shared__ unsigned cnt8[NBATCH];

  const int tid  = threadIdx.x;
  const int lane = tid & 63;
  const int wave = tid >> 6;
  const int wr = wave >> 1, wc = wave & 1;
  const int lr  = lane & 15;
  const int lkb = lane >> 4;
  const int n0  = blockIdx.x * 128;
  const int bcol = wc * 64 + lr;

  if (tid < 128) {
    int node = n0 + tid;
    nbat_s[tid] = (node < NN) ? batch[node < NN ? node : 0] : 0;
  }
  for (int i = tid; i < NBATCH * 128; i += 256) (&red[0][0])[i] = 0.f;
  if (tid < NBATCH) cnt8[tid] = 0;

  f32x4 acc[4][4];
#pragma unroll
  for (int m = 0; m < 4; ++m)
#pragma unroll
    for (int n = 0; n < 4; ++n) { acc[m][n][0]=0.f; acc[m][n][1]=0.f; acc[m][n][2]=0.f; acc[m][n][3]=0.f; }

  __syncthreads();

  auto stage_bf = [&](int buf, int c) {   // c==0: xbf ; c==2: ubf
#pragma unroll
    for (int i = 0; i < 8; ++i) {
      int rr = wave * 32 + i * 4 + (lane >> 4);
      int node = n0 + rr; if (node >= NN) node = 0;
      const u16* rp = (c == 0) ? (xbf + (size_t)node * DD)
                               : (ubf + (size_t)nbat_s[rr] * DD);
      int sd = lane & 15;
      const u16* src = rp + ((sd ^ (rr & 7)) << 3);
      u16* dst = &As[buf][(wave * 32 + i * 4) * 128];
      glds16(src, dst);
    }
  };

  auto stage_agg = [&](int buf) {
#pragma unroll
    for (int j = 0; j < 8; ++j) {
      int t = j * 64 + lane;
      int rr = wave * 32 + (t >> 4);
      int k  = t & 15;
      int node = n0 + rr; if (node >= NN) node = 0;
      const float* p = aggx + (size_t)node * DD + k * 8;
      f32x4 a = *(const f32x4*)p;
      f32x4 b = *(const f32x4*)(p + 4);
      u16x8 v;
      v[0]=f2bf(a[0]); v[1]=f2bf(a[1]); v[2]=f2bf(a[2]); v[3]=f2bf(a[3]);
      v[4]=f2bf(b[0]); v[5]=f2bf(b[1]); v[6]=f2bf(b[2]); v[7]=f2bf(b[3]);
      *(u16x8*)&As[buf][rr * 128 + ((k ^ (rr & 7)) << 3)] = v;
    }
  };

  auto compute = [&](const u16* AsBuf, const u16* wsrc) {
#pragma unroll
    for (int kk = 0; kk < 4; ++kk) {
      const int k0 = kk * 32 + lkb * 8;
      bf16x8 af[4], bfv[4];
#pragma unroll
      for (int m = 0; m < 4; ++m) {
        int g = wr * 64 + m * 16 + lr;
        int slot = kk * 4 + lkb;
        af[m] = *(const bf16x8*)(AsBuf + g * 128 + ((slot ^ (g & 7)) << 3));
      }
#pragma unroll
      for (int n = 0; n < 4; ++n)
        bfv[n] = *(const bf16x8*)(wsrc + ((bcol + n * 16) << 7) + k0);
#pragma unroll
      for (int m = 0; m < 4; ++m)
#pragma unroll
        for (int n = 0; n < 4; ++n)
          acc[m][n] = __builtin_amdgcn_mfma_f32_16x16x32_bf16(af[m], bfv[n], acc[m][n], 0, 0, 0);
    }
  };

  auto epi_relu = [&](u16* HsBuf, const float* bias) {
#pragma unroll
    for (int n = 0; n < 4; ++n) {
      int colg = wc * 64 + n * 16 + lr;
      float bv = bias[colg];
      int slot = colg >> 3;
#pragma unroll
      for (int m = 0; m < 4; ++m)
#pragma unroll
        for (int r = 0; r < 4; ++r) {
          int rowg = wr * 64 + m * 16 + lkb * 4 + r;
          float v = fmaxf(acc[m][n][r] + bv, 0.f);
          HsBuf[rowg * 128 + ((slot ^ (rowg & 7)) << 3) + (colg & 7)] = f2bf(v);
          acc[m][n][r] = 0.f;
        }
    }
  };

  // layer 1: 3 chunks (x | agg | u)
  stage_bf(0, 0);
  __syncthreads();
  stage_agg(1); compute(As[0], w1);               __syncthreads();
  stage_bf(0, 2); compute(As[1], w1 + (1 << 14)); __syncthreads();
                  compute(As[0], w1 + (2 << 14));
  epi_relu(As[1], b1);
  __syncthreads();
  compute(As[1], w2);
  __syncthreads();
  epi_relu(As[0], b2);
  __syncthreads();
  compute(As[0], w3);

  // epilogue 3: x_out overwrites agg rows; node-mean partials
#pragma unroll
  for (int n = 0; n < 4; ++n) {
    int colg = wc * 64 + n * 16 + lr;
    float bias = b3[colg];
#pragma unroll
    for (int m = 0; m < 4; ++m)
#pragma unroll
      for (int r = 0; r < 4; ++r) {
        int rowg = wr * 64 + m * 16 + lkb * 4 + r;
        int node = n0 + rowg;
        if (node < NN) {
          float v = acc[m][n][r] + bias;
          aggx[(size_t)node * DD + colg] = v;
          atomicAdd(&red[nbat_s[rowg]][colg], v);
        }
      }
  }
  if (tid < 128 && (n0 + tid) < NN) atomicAdd(&cnt8[nbat_s[tid]], 1u);
  __syncthreads();
  for (int i = tid; i < NBATCH * 128; i += 256) atomicAdd(&nsum[i], (&red[0][0])[i]);
  if (tid < NBATCH) atomicAdd(&ncnt[tid], cnt8[tid]);
}

// ---------------- Global MLP (fp32, tiny) ----------------
__global__ void global_kernel(
    const float* __restrict__ u,
    const float* __restrict__ nsum, const unsigned* __restrict__ ncnt,
    const float* __restrict__ esum, const unsigned* __restrict__ ecnt,
    const float* __restrict__ gW1, const float* __restrict__ gb1,
    const float* __restrict__ gW2, const float* __restrict__ gb2,
    const float* __restrict__ gW3, const float* __restrict__ gb3,
    float* __restrict__ u_out)
{
  __shared__ float gin[NBATCH][384];
  __shared__ float h1[NBATCH][128];
  __shared__ float h2[NBATCH][128];
  int tid = threadIdx.x;
  for (int i = tid; i < NBATCH * 128; i += 256) {
    int r = i >> 7, c = i & 127;
    float nc = (float)(ncnt[r] < 1u ? 1u : ncnt[r]);
    float ec = (float)(ecnt[r] < 1u ? 1u : ecnt[r]);
    gin[r][c] = u[i];
    gin[r][128 + c] = nsum[i] / nc;
    gin[r][256 + c] = esum[i] / ec;
  }
  __syncthreads();
  for (int o = tid; o < NBATCH * 128; o += 256) {
    int r = o >> 7, n = o & 127;
    float s = gb1[n];
    for (int k = 0; k < 384; ++k) s += gin[r][k] * gW1[k * 128 + n];
    h1[r][n] = fmaxf(s, 0.f);
  }
  __syncthreads();
  for (int o = tid; o < NBATCH * 128; o += 256) {
    int r = o >> 7, n = o & 127;
    float s = gb2[n];
    for (int k = 0; k < 128; ++k) s += h1[r][k] * gW2[k * 128 + n];
    h2[r][n] = fmaxf(s, 0.f);
  }
  __syncthreads();
  for (int o = tid; o < NBATCH * 128; o += 256) {
    int r = o >> 7, n = o & 127;
    float s = gb3[n];
    for (int k = 0; k < 128; ++k) s += h2[r][k] * gW3[k * 128 + n];
    u_out[o] = s;
  }
}

extern "C" void kernel_launch(void* const* d_in, const int* in_sizes, int n_in,
                              void* d_out, int out_size, void* d_ws, size_t ws_size,
                              hipStream_t stream) {
  const float* x          = (const float*)d_in[0];
  const int*   edge_index = (const int*)d_in[1];
  const float* edge_attr  = (const float*)d_in[2];
  const float* u          = (const float*)d_in[3];
  const int*   batch      = (const int*)d_in[4];
  const float* eW1 = (const float*)d_in[5];  const float* eb1 = (const float*)d_in[6];
  const float* eW2 = (const float*)d_in[7];  const float* eb2 = (const float*)d_in[8];
  const float* eW3 = (const float*)d_in[9];  const float* eb3 = (const float*)d_in[10];
  const float* nW1 = (const float*)d_in[11]; const float* nb1 = (const float*)d_in[12];
  const float* nW2 = (const float*)d_in[13]; const float* nb2 = (const float*)d_in[14];
  const float* nW3 = (const float*)d_in[15]; const float* nb3 = (const float*)d_in[16];
  const float* gW1 = (const float*)d_in[17]; const float* gb1 = (const float*)d_in[18];
  const float* gW2 = (const float*)d_in[19]; const float* gb2 = (const float*)d_in[20];
  const float* gW3 = (const float*)d_in[21]; const float* gb3 = (const float*)d_in[22];

  float* out      = (float*)d_out;
  float* xout_agg = out;                                  // [NN][128]: agg then x_out
  float* edge_out = out + (size_t)NN * DD;                // [NE][128]
  float* u_out    = out + (size_t)(NN + NE) * DD;         // [8][128]

  char* ws = (char*)d_ws;
  u16* wE1t = (u16*)(ws + 0);         // 131072
  u16* wE2t = (u16*)(ws + 131072);    // 32768
  u16* wE3t = (u16*)(ws + 163840);    // 32768
  u16* wN1t = (u16*)(ws + 196608);    // 98304
  u16* wN2t = (u16*)(ws + 294912);    // 32768
  u16* wN3t = (u16*)(ws + 327680);    // 32768
  float*    esum = (float*)(ws + 360448);     // 4096
  float*    nsum = (float*)(ws + 364544);     // 4096
  unsigned* ecnt = (unsigned*)(ws + 368640);  // 32
  unsigned* ncnt = (unsigned*)(ws + 368672);  // 32
  u16*      ubf  = (u16*)(ws + 369664);       // 2048
  u16*      xbf  = (u16*)(ws + 393216);       // 12,800,000 -> ends 13,193,216
  const size_t EABF_OFF = 13193216;
  const size_t EABF_END = EABF_OFF + (size_t)NE * DD * 2; // 115,593,216
  u16* eabf = (ws_size >= EABF_END) ? (u16*)(ws + EABF_OFF) : nullptr;

  // zero agg region (x_out part of d_out) and stat accumulators — every launch
  hipMemsetAsync(d_out, 0, (size_t)NN * DD * sizeof(float), stream);
  hipMemsetAsync(ws + 360448, 0, 8288, stream);

  wconv_kernel<<<256, 256, 0, stream>>>(eW1, wE1t, 512);
  wconv_kernel<<<64, 256, 0, stream>>>(eW2, wE2t, 128);
  wconv_kernel<<<64, 256, 0, stream>>>(eW3, wE3t, 128);
  wconv_kernel<<<192, 256, 0, stream>>>(nW1, wN1t, 384);
  wconv_kernel<<<64, 256, 0, stream>>>(nW2, wN2t, 128);
  wconv_kernel<<<64, 256, 0, stream>>>(nW3, wN3t, 128);
  xconv_kernel<<<6250, 256, 0, stream>>>(x, xbf, NN * DD / 4);
  xconv_kernel<<<1, 256, 0, stream>>>(u, ubf, NBATCH * DD / 4);
  if (eabf)
    xconv_kernel<<<50000, 256, 0, stream>>>(edge_attr, eabf, NE * DD / 4);

  edge_kernel<<<NE / 128, 256, 0, stream>>>(
      xbf, eabf, edge_attr, ubf, edge_index, batch,
      wE1t, wE2t, wE3t, eb1, eb2, eb3,
      edge_out, xout_agg, esum, ecnt);

  node_kernel<<<(NN + 127) / 128, 256, 0, stream>>>(
      xbf, xout_agg, ubf, batch,
      wN1t, wN2t, wN3t, nb1, nb2, nb3,
      nsum, ncnt);

  global_kernel<<<1, 256, 0, stream>>>(
      u, nsum, ncnt, esum, ecnt,
      gW1, gb1, gW2, gb2, gW3, gb3, u_out);
}

// Round 5
// 635.845 us; speedup vs baseline: 1.2002x; 1.0190x over previous
//
#include <hip/hip_runtime.h>

#define NN 50000
#define NE 400000
#define NBATCH 8
#define DD 128

typedef unsigned short u16;
typedef __attribute__((ext_vector_type(8))) short bf16x8;
typedef __attribute__((ext_vector_type(8))) unsigned short u16x8;
typedef __attribute__((ext_vector_type(4))) unsigned short u16x4;
typedef __attribute__((ext_vector_type(4))) float f32x4;

__device__ __forceinline__ u16 f2bf(float f) {
  union { float f; unsigned u; } a; a.f = f;
  unsigned r = a.u + 0x7fffu + ((a.u >> 16) & 1u);
  return (u16)(r >> 16);
}

__device__ __forceinline__ void glds16(const void* g, void* l) {
  __builtin_amdgcn_global_load_lds(
      (const __attribute__((address_space(1))) unsigned*)g,
      (__attribute__((address_space(3))) unsigned*)l, 16, 0, 0);
}

// Convert+transpose fp32 weight [K][128] -> bf16 chunked [K/128][128 n][128 k]
__global__ void wconv_kernel(const float* __restrict__ src, u16* __restrict__ dst, int K) {
  int idx = blockIdx.x * 256 + threadIdx.x;
  if (idx >= K * 128) return;
  int k = idx >> 7, n = idx & 127;
  dst[((k >> 7) << 14) + (n << 7) + (k & 127)] = f2bf(src[idx]);
}

// fp32 -> bf16 flat copy
__global__ void xconv_kernel(const float* __restrict__ x, u16* __restrict__ xbf, int total4) {
  int i = blockIdx.x * 256 + threadIdx.x;
  if (i >= total4) return;
  f32x4 v = ((const f32x4*)x)[i];
  u16x4 o; o[0]=f2bf(v[0]); o[1]=f2bf(v[1]); o[2]=f2bf(v[2]); o[3]=f2bf(v[3]);
  ((u16x4*)xbf)[i] = o;
}

// ---------------- Edge MLP: 64-edge tile, ALL-upfront staging ----------------
// Key idea: issue all 16 global_load_lds per wave (4 chunks x 4) BEFORE one
// barrier -> 64KB in flight per block (128KB/CU), ONE latency exposure for
// the whole K=512 layer, then an uninterrupted MFMA burst.
__global__ __launch_bounds__(256, 2) void edge_kernel(
    const u16* __restrict__ xbf, const u16* __restrict__ eabf /*may be null*/,
    const float* __restrict__ ea_f32, const u16* __restrict__ ubf,
    const int* __restrict__ edge_index, const int* __restrict__ batch,
    const u16* __restrict__ w1, const u16* __restrict__ w2, const u16* __restrict__ w3,
    const float* __restrict__ b1, const float* __restrict__ b2, const float* __restrict__ b3,
    float* __restrict__ edge_out, float* agg,
    float* __restrict__ esum, unsigned* __restrict__ ecnt)
{
  __shared__ u16 As[4][64 * 128];       // 64 KB: all four K-chunks
  __shared__ float red[NBATCH][128];
  __shared__ int rows_s[64], cols_s[64], ebat_s[64];
  __shared__ unsigned cnt8[NBATCH];

  const int tid  = threadIdx.x;
  const int lane = tid & 63;
  const int wave = tid >> 6;
  const int wc   = wave;                // 4 waves tile N=128 as 4 x 32 cols
  const int lr   = lane & 15;
  const int lkb  = lane >> 4;
  const int e0   = blockIdx.x * 64;

  if (tid < 64) {
    int r = edge_index[e0 + tid];
    int c = edge_index[NE + e0 + tid];
    rows_s[tid] = r; cols_s[tid] = c;
    ebat_s[tid] = batch[r];
  }
  for (int i = tid; i < NBATCH * 128; i += 256) (&red[0][0])[i] = 0.f;
  if (tid < NBATCH) cnt8[tid] = 0;

  f32x4 acc[4][2];
#pragma unroll
  for (int m = 0; m < 4; ++m)
#pragma unroll
    for (int n = 0; n < 2; ++n) { acc[m][n][0]=0.f; acc[m][n][1]=0.f; acc[m][n][2]=0.f; acc[m][n][3]=0.f; }

  __syncthreads();  // indices visible

  // ---- stage ALL 4 chunks up front (16 glds16 per wave; rows wave*16..+15)
#pragma unroll
  for (int c = 0; c < 4; ++c) {
    if (c == 2 && eabf == nullptr) continue;   // fallback below
#pragma unroll
    for (int i = 0; i < 4; ++i) {
      int rr = wave * 16 + i * 4 + (lane >> 4);
      const u16* rp;
      if (c == 0)      rp = xbf + (size_t)rows_s[rr] * DD;
      else if (c == 1) rp = xbf + (size_t)cols_s[rr] * DD;
      else if (c == 2) rp = eabf + (size_t)(e0 + rr) * DD;
      else             rp = ubf + (size_t)ebat_s[rr] * DD;
      const u16* src = rp + (((lane & 15) ^ (rr & 7)) << 3);  // inverse-swizzled source
      u16* dst = &As[c][(wave * 16 + i * 4) * 128];           // linear wave-uniform dest
      glds16(src, dst);
    }
  }
  if (eabf == nullptr) {
    // fp32 fallback for edge_attr: reg-stage + cvt + swizzled ds_write
#pragma unroll
    for (int j = 0; j < 4; ++j) {
      int idx = j * 64 + lane;
      int rr = wave * 16 + (idx >> 4);
      int k  = idx & 15;
      const float* p = ea_f32 + (size_t)(e0 + rr) * DD + k * 8;
      f32x4 a = *(const f32x4*)p;
      f32x4 b = *(const f32x4*)(p + 4);
      u16x8 v;
      v[0]=f2bf(a[0]); v[1]=f2bf(a[1]); v[2]=f2bf(a[2]); v[3]=f2bf(a[3]);
      v[4]=f2bf(b[0]); v[5]=f2bf(b[1]); v[6]=f2bf(b[2]); v[7]=f2bf(b[3]);
      *(u16x8*)&As[2][rr * 128 + ((k ^ (rr & 7)) << 3)] = v;
    }
  }
  __syncthreads();  // one drain for the whole layer-1 K

  auto compute = [&](const u16* AsBuf, const u16* wsrc) {
#pragma unroll
    for (int kk = 0; kk < 4; ++kk) {
      const int k0 = kk * 32 + lkb * 8;
      bf16x8 af[4], bfv[2];
#pragma unroll
      for (int m = 0; m < 4; ++m) {
        int g = m * 16 + lr;
        int slot = kk * 4 + lkb;
        af[m] = *(const bf16x8*)(AsBuf + g * 128 + ((slot ^ (g & 7)) << 3));
      }
#pragma unroll
      for (int n = 0; n < 2; ++n)
        bfv[n] = *(const bf16x8*)(wsrc + ((wc * 32 + n * 16 + lr) << 7) + k0);
#pragma unroll
      for (int m = 0; m < 4; ++m)
#pragma unroll
        for (int n = 0; n < 2; ++n)
          acc[m][n] = __builtin_amdgcn_mfma_f32_16x16x32_bf16(af[m], bfv[n], acc[m][n], 0, 0, 0);
    }
  };

  auto epi_relu = [&](u16* HsBuf, const float* bias) {
#pragma unroll
    for (int n = 0; n < 2; ++n) {
      int colg = wc * 32 + n * 16 + lr;
      float bv = bias[colg];
      int slot = colg >> 3;
#pragma unroll
      for (int m = 0; m < 4; ++m)
#pragma unroll
        for (int r = 0; r < 4; ++r) {
          int rowg = m * 16 + lkb * 4 + r;
          float v = fmaxf(acc[m][n][r] + bv, 0.f);
          HsBuf[rowg * 128 + ((slot ^ (rowg & 7)) << 3) + (colg & 7)] = f2bf(v);
          acc[m][n][r] = 0.f;
        }
    }
  };

  // ---- layer 1: uninterrupted 128-MFMA burst over K=512
  compute(As[0], w1);
  compute(As[1], w1 + (1 << 14));
  compute(As[2], w1 + (2 << 14));
  compute(As[3], w1 + (3 << 14));
  __syncthreads();                 // everyone done reading As[0]
  epi_relu(As[0], b1);
  __syncthreads();
  compute(As[0], w2);
  __syncthreads();                 // done reading As[1]... (already), done As[0] reads
  epi_relu(As[1], b2);
  __syncthreads();
  compute(As[1], w3);

  // epilogue 3: edge_out + agg scatter atomics + per-graph esum partials
#pragma unroll
  for (int n = 0; n < 2; ++n) {
    int colg = wc * 32 + n * 16 + lr;
    float bias = b3[colg];
#pragma unroll
    for (int m = 0; m < 4; ++m)
#pragma unroll
      for (int r = 0; r < 4; ++r) {
        int rowg = m * 16 + lkb * 4 + r;
        float v = acc[m][n][r] + bias;
        edge_out[(size_t)(e0 + rowg) * DD + colg] = v;
        atomicAdd(&agg[(size_t)cols_s[rowg] * DD + colg], v);
        atomicAdd(&red[ebat_s[rowg]][colg], v);
      }
  }
  if (tid < 64) atomicAdd(&cnt8[ebat_s[tid]], 1u);
  __syncthreads();
  for (int i = tid; i < NBATCH * 128; i += 256) atomicAdd(&esum[i], (&red[0][0])[i]);
  if (tid < NBATCH) atomicAdd(&ecnt[tid], cnt8[tid]);
}

// ---------------- Node MLP: 2-phase pipelined (unchanged from R4) ----------------
__global__ __launch_bounds__(256, 2) void node_kernel(
    const u16* __restrict__ xbf, float* aggx /* agg in, x_out out */,
    const u16* __restrict__ ubf, const int* __restrict__ batch,
    const u16* __restrict__ w1, const u16* __restrict__ w2, const u16* __restrict__ w3,
    const float* __restrict__ b1, const float* __restrict__ b2, const float* __restrict__ b3,
    float* __restrict__ nsum, unsigned* __restrict__ ncnt)
{
  __shared__ u16 As[2][128 * 128];
  __shared__ float red[NBATCH][128];
  __shared__ int nbat_s[128];
  __shared__ unsigned cnt8[NBATCH];

  const int tid  = threadIdx.x;
  const int lane = tid & 63;
  const int wave = tid >> 6;
  const int wr = wave >> 1, wc = wave & 1;
  const int lr  = lane & 15;
  const int lkb = lane >> 4;
  const int n0  = blockIdx.x * 128;
  const int bcol = wc * 64 + lr;

  if (tid < 128) {
    int node = n0 + tid;
    nbat_s[tid] = (node < NN) ? batch[node] : 0;
  }
  for (int i = tid; i < NBATCH * 128; i += 256) (&red[0][0])[i] = 0.f;
  if (tid < NBATCH) cnt8[tid] = 0;

  f32x4 acc[4][4];
#pragma unroll
  for (int m = 0; m < 4; ++m)
#pragma unroll
    for (int n = 0; n < 4; ++n) { acc[m][n][0]=0.f; acc[m][n][1]=0.f; acc[m][n][2]=0.f; acc[m][n][3]=0.f; }

  __syncthreads();

  auto stage_bf = [&](int buf, int c) {   // c==0: xbf ; c==2: ubf
#pragma unroll
    for (int i = 0; i < 8; ++i) {
      int rr = wave * 32 + i * 4 + (lane >> 4);
      int node = n0 + rr; if (node >= NN) node = 0;
      const u16* rp = (c == 0) ? (xbf + (size_t)node * DD)
                               : (ubf + (size_t)nbat_s[rr] * DD);
      int sd = lane & 15;
      const u16* src = rp + ((sd ^ (rr & 7)) << 3);
      u16* dst = &As[buf][(wave * 32 + i * 4) * 128];
      glds16(src, dst);
    }
  };

  auto stage_agg = [&](int buf) {
#pragma unroll
    for (int j = 0; j < 8; ++j) {
      int t = j * 64 + lane;
      int rr = wave * 32 + (t >> 4);
      int k  = t & 15;
      int node = n0 + rr; if (node >= NN) node = 0;
      const float* p = aggx + (size_t)node * DD + k * 8;
      f32x4 a = *(const f32x4*)p;
      f32x4 b = *(const f32x4*)(p + 4);
      u16x8 v;
      v[0]=f2bf(a[0]); v[1]=f2bf(a[1]); v[2]=f2bf(a[2]); v[3]=f2bf(a[3]);
      v[4]=f2bf(b[0]); v[5]=f2bf(b[1]); v[6]=f2bf(b[2]); v[7]=f2bf(b[3]);
      *(u16x8*)&As[buf][rr * 128 + ((k ^ (rr & 7)) << 3)] = v;
    }
  };

  auto compute = [&](const u16* AsBuf, const u16* wsrc) {
#pragma unroll
    for (int kk = 0; kk < 4; ++kk) {
      const int k0 = kk * 32 + lkb * 8;
      bf16x8 af[4], bfv[4];
#pragma unroll
      for (int m = 0; m < 4; ++m) {
        int g = wr * 64 + m * 16 + lr;
        int slot = kk * 4 + lkb;
        af[m] = *(const bf16x8*)(AsBuf + g * 128 + ((slot ^ (g & 7)) << 3));
      }
#pragma unroll
      for (int n = 0; n < 4; ++n)
        bfv[n] = *(const bf16x8*)(wsrc + ((bcol + n * 16) << 7) + k0);
#pragma unroll
      for (int m = 0; m < 4; ++m)
#pragma unroll
        for (int n = 0; n < 4; ++n)
          acc[m][n] = __builtin_amdgcn_mfma_f32_16x16x32_bf16(af[m], bfv[n], acc[m][n], 0, 0, 0);
    }
  };

  auto epi_relu = [&](u16* HsBuf, const float* bias) {
#pragma unroll
    for (int n = 0; n < 4; ++n) {
      int colg = wc * 64 + n * 16 + lr;
      float bv = bias[colg];
      int slot = colg >> 3;
#pragma unroll
      for (int m = 0; m < 4; ++m)
#pragma unroll
        for (int r = 0; r < 4; ++r) {
          int rowg = wr * 64 + m * 16 + lkb * 4 + r;
          float v = fmaxf(acc[m][n][r] + bv, 0.f);
          HsBuf[rowg * 128 + ((slot ^ (rowg & 7)) << 3) + (colg & 7)] = f2bf(v);
          acc[m][n][r] = 0.f;
        }
    }
  };

  // layer 1: 3 chunks (x | agg | u)
  stage_bf(0, 0);
  __syncthreads();
  stage_agg(1); compute(As[0], w1);               __syncthreads();
  stage_bf(0, 2); compute(As[1], w1 + (1 << 14)); __syncthreads();
                  compute(As[0], w1 + (2 << 14));
  epi_relu(As[1], b1);
  __syncthreads();
  compute(As[1], w2);
  __syncthreads();
  epi_relu(As[0], b2);
  __syncthreads();
  compute(As[0], w3);

  // epilogue 3: x_out overwrites agg rows; node-mean partials
#pragma unroll
  for (int n = 0; n < 4; ++n) {
    int colg = wc * 64 + n * 16 + lr;
    float bias = b3[colg];
#pragma unroll
    for (int m = 0; m < 4; ++m)
#pragma unroll
      for (int r = 0; r < 4; ++r) {
        int rowg = wr * 64 + m * 16 + lkb * 4 + r;
        int node = n0 + rowg;
        if (node < NN) {
          float v = acc[m][n][r] + bias;
          aggx[(size_t)node * DD + colg] = v;
          atomicAdd(&red[nbat_s[rowg]][colg], v);
        }
      }
  }
  if (tid < 128 && (n0 + tid) < NN) atomicAdd(&cnt8[nbat_s[tid]], 1u);
  __syncthreads();
  for (int i = tid; i < NBATCH * 128; i += 256) atomicAdd(&nsum[i], (&red[0][0])[i]);
  if (tid < NBATCH) atomicAdd(&ncnt[tid], cnt8[tid]);
}

// ---------------- Global MLP (fp32, tiny) ----------------
__global__ void global_kernel(
    const float* __restrict__ u,
    const float* __restrict__ nsum, const unsigned* __restrict__ ncnt,
    const float* __restrict__ esum, const unsigned* __restrict__ ecnt,
    const float* __restrict__ gW1, const float* __restrict__ gb1,
    const float* __restrict__ gW2, const float* __restrict__ gb2,
    const float* __restrict__ gW3, const float* __restrict__ gb3,
    float* __restrict__ u_out)
{
  __shared__ float gin[NBATCH][384];
  __shared__ float h1[NBATCH][128];
  __shared__ float h2[NBATCH][128];
  int tid = threadIdx.x;
  for (int i = tid; i < NBATCH * 128; i += 256) {
    int r = i >> 7, c = i & 127;
    float nc = (float)(ncnt[r] < 1u ? 1u : ncnt[r]);
    float ec = (float)(ecnt[r] < 1u ? 1u : ecnt[r]);
    gin[r][c] = u[i];
    gin[r][128 + c] = nsum[i] / nc;
    gin[r][256 + c] = esum[i] / ec;
  }
  __syncthreads();
  for (int o = tid; o < NBATCH * 128; o += 256) {
    int r = o >> 7, n = o & 127;
    float s = gb1[n];
    for (int k = 0; k < 384; ++k) s += gin[r][k] * gW1[k * 128 + n];
    h1[r][n] = fmaxf(s, 0.f);
  }
  __syncthreads();
  for (int o = tid; o < NBATCH * 128; o += 256) {
    int r = o >> 7, n = o & 127;
    float s = gb2[n];
    for (int k = 0; k < 128; ++k) s += h1[r][k] * gW2[k * 128 + n];
    h2[r][n] = fmaxf(s, 0.f);
  }
  __syncthreads();
  for (int o = tid; o < NBATCH * 128; o += 256) {
    int r = o >> 7, n = o & 127;
    float s = gb3[n];
    for (int k = 0; k < 128; ++k) s += h2[r][k] * gW3[k * 128 + n];
    u_out[o] = s;
  }
}

extern "C" void kernel_launch(void* const* d_in, const int* in_sizes, int n_in,
                              void* d_out, int out_size, void* d_ws, size_t ws_size,
                              hipStream_t stream) {
  const float* x          = (const float*)d_in[0];
  const int*   edge_index = (const int*)d_in[1];
  const float* edge_attr  = (const float*)d_in[2];
  const float* u          = (const float*)d_in[3];
  const int*   batch      = (const int*)d_in[4];
  const float* eW1 = (const float*)d_in[5];  const float* eb1 = (const float*)d_in[6];
  const float* eW2 = (const float*)d_in[7];  const float* eb2 = (const float*)d_in[8];
  const float* eW3 = (const float*)d_in[9];  const float* eb3 = (const float*)d_in[10];
  const float* nW1 = (const float*)d_in[11]; const float* nb1 = (const float*)d_in[12];
  const float* nW2 = (const float*)d_in[13]; const float* nb2 = (const float*)d_in[14];
  const float* nW3 = (const float*)d_in[15]; const float* nb3 = (const float*)d_in[16];
  const float* gW1 = (const float*)d_in[17]; const float* gb1 = (const float*)d_in[18];
  const float* gW2 = (const float*)d_in[19]; const float* gb2 = (const float*)d_in[20];
  const float* gW3 = (const float*)d_in[21]; const float* gb3 = (const float*)d_in[22];

  float* out      = (float*)d_out;
  float* xout_agg = out;                                  // [NN][128]: agg then x_out
  float* edge_out = out + (size_t)NN * DD;                // [NE][128]
  float* u_out    = out + (size_t)(NN + NE) * DD;         // [8][128]

  char* ws = (char*)d_ws;
  u16* wE1t = (u16*)(ws + 0);         // 131072
  u16* wE2t = (u16*)(ws + 131072);    // 32768
  u16* wE3t = (u16*)(ws + 163840);    // 32768
  u16* wN1t = (u16*)(ws + 196608);    // 98304
  u16* wN2t = (u16*)(ws + 294912);    // 32768
  u16* wN3t = (u16*)(ws + 327680);    // 32768
  float*    esum = (float*)(ws + 360448);     // 4096
  float*    nsum = (float*)(ws + 364544);     // 4096
  unsigned* ecnt = (unsigned*)(ws + 368640);  // 32
  unsigned* ncnt = (unsigned*)(ws + 368672);  // 32
  u16*      ubf  = (u16*)(ws + 369664);       // 2048
  u16*      xbf  = (u16*)(ws + 393216);       // 12,800,000 -> ends 13,193,216
  const size_t EABF_OFF = 13193216;
  const size_t EABF_END = EABF_OFF + (size_t)NE * DD * 2; // 115,593,216
  u16* eabf = (ws_size >= EABF_END) ? (u16*)(ws + EABF_OFF) : nullptr;

  // zero agg region (x_out part of d_out) and stat accumulators — every launch
  hipMemsetAsync(d_out, 0, (size_t)NN * DD * sizeof(float), stream);
  hipMemsetAsync(ws + 360448, 0, 8288, stream);

  wconv_kernel<<<256, 256, 0, stream>>>(eW1, wE1t, 512);
  wconv_kernel<<<64, 256, 0, stream>>>(eW2, wE2t, 128);
  wconv_kernel<<<64, 256, 0, stream>>>(eW3, wE3t, 128);
  wconv_kernel<<<192, 256, 0, stream>>>(nW1, wN1t, 384);
  wconv_kernel<<<64, 256, 0, stream>>>(nW2, wN2t, 128);
  wconv_kernel<<<64, 256, 0, stream>>>(nW3, wN3t, 128);
  xconv_kernel<<<6250, 256, 0, stream>>>(x, xbf, NN * DD / 4);
  xconv_kernel<<<1, 256, 0, stream>>>(u, ubf, NBATCH * DD / 4);
  if (eabf)
    xconv_kernel<<<50000, 256, 0, stream>>>(edge_attr, eabf, NE * DD / 4);

  edge_kernel<<<NE / 64, 256, 0, stream>>>(
      xbf, eabf, edge_attr, ubf, edge_index, batch,
      wE1t, wE2t, wE3t, eb1, eb2, eb3,
      edge_out, xout_agg, esum, ecnt);

  node_kernel<<<(NN + 127) / 128, 256, 0, stream>>>(
      xbf, xout_agg, ubf, batch,
      wN1t, wN2t, wN3t, nb1, nb2, nb3,
      nsum, ncnt);

  global_kernel<<<1, 256, 0, stream>>>(
      u, nsum, ncnt, esum, ecnt,
      gW1, gb1, gW2, gb2, gW3, gb3, u_out);
}